// Round 1
// baseline (5132.922 us; speedup 1.0000x reference)
//
#include <hip/hip_runtime.h>
#include <math.h>

#define BQ 32
#define TQ 512
#define DQ 768
#define KQ 256
#define HQ 512
#define G4 2048
#define SROW 772   // state row: h[0:512) | A[512:768) | S at [768] | pad to 772
#define NWG 512    // 8 groups x 64 WGs
#define NTHR 256
#define NBG 4      // batches per group

typedef float f32x4 __attribute__((ext_vector_type(4)));

__device__ __forceinline__ void waitcnt0() {
  asm volatile("s_waitcnt vmcnt(0) lgkmcnt(0)" ::: "memory");
}
__device__ __forceinline__ void st_agent(float* p, float v) {
  asm volatile("global_store_dword %0, %1, off sc0 sc1" :: "v"(p), "v"(v) : "memory");
}
__device__ __forceinline__ int ld_flag(const int* p) {
  int v;
  asm volatile("global_load_dword %0, %1, off sc0 sc1\ns_waitcnt vmcnt(0)"
               : "=v"(v) : "v"(p) : "memory");
  return v;
}
__device__ __forceinline__ void wg_wait(const int* flags, int target) {
  const int lane = threadIdx.x & 63;
  for (;;) {
    int v = ld_flag(flags + lane);
    if (__all(v >= target)) break;
    __builtin_amdgcn_s_sleep(1);
  }
  __syncthreads();
}
__device__ __forceinline__ void wg_signal(int* flag, int val) {
  waitcnt0();
  __syncthreads();
  if (threadIdx.x == 0)
    asm volatile("global_store_dword %0, %1, off sc0 sc1" :: "v"(flag), "v"(val) : "memory");
}
__device__ __forceinline__ float sigm(float x) { return 1.f / (1.f + __expf(-x)); }

// ---------------- P1: Gram matrix G[b][t][tau] = x_t . x_tau ----------------
__global__ void __launch_bounds__(256) gram_k(const float* __restrict__ X,
                                              float* __restrict__ Gm) {
  __shared__ __align__(16) float As[64 * 33];
  __shared__ __align__(16) float Bs[64 * 33];
  const int bid = blockIdx.x;
  const int b = blockIdx.y;
  int I = 0, base = 0;
  while (base + I + 1 <= bid) { base += I + 1; ++I; }
  const int J = bid - base;
  const int t0 = I * 64, u0 = J * 64;
  const float* Xb = X + (size_t)b * TQ * DQ;
  const int ty = threadIdx.x >> 4, tx = threadIdx.x & 15;
  const int sc = threadIdx.x & 31, sr = threadIdx.x >> 5;
  float acc[4][4];
#pragma unroll
  for (int i = 0; i < 4; ++i)
#pragma unroll
    for (int j = 0; j < 4; ++j) acc[i][j] = 0.f;
  for (int k0 = 0; k0 < DQ; k0 += 32) {
#pragma unroll
    for (int rr = 0; rr < 8; ++rr) {
      const int r = rr * 8 + sr;
      As[r * 33 + sc] = Xb[(size_t)(t0 + r) * DQ + k0 + sc];
      Bs[r * 33 + sc] = Xb[(size_t)(u0 + r) * DQ + k0 + sc];
    }
    __syncthreads();
#pragma unroll
    for (int k = 0; k < 32; ++k) {
      float av[4], bv[4];
#pragma unroll
      for (int i = 0; i < 4; ++i) av[i] = As[(ty * 4 + i) * 33 + k];
#pragma unroll
      for (int j = 0; j < 4; ++j) bv[j] = Bs[(tx * 4 + j) * 33 + k];
#pragma unroll
      for (int i = 0; i < 4; ++i)
#pragma unroll
        for (int j = 0; j < 4; ++j) acc[i][j] += av[i] * bv[j];
    }
    __syncthreads();
  }
  float* gb = Gm + (size_t)b * TQ * TQ;
#pragma unroll
  for (int i = 0; i < 4; ++i) {
    f32x4 o;
    o.x = acc[i][0]; o.y = acc[i][1]; o.z = acc[i][2]; o.w = acc[i][3];
    *(f32x4*)&gb[(size_t)(t0 + ty * 4 + i) * TQ + u0 + tx * 4] = o;
  }
}

// ---------------- P2: row softmax (tau < t) in place + S[b][t] ----------------
__global__ void __launch_bounds__(256) smax_k(float* __restrict__ Gm,
                                              float* __restrict__ Sv,
                                              const float* __restrict__ cgp,
                                              const float* __restrict__ cbp) {
  const int t = blockIdx.x + 1;   // 1..511
  const int b = blockIdx.y;
  const int tid = threadIdx.x;
  const int lane = tid & 63;
  const int wv = tid >> 6;
  __shared__ float row[TQ];
  __shared__ float r1[4], r2[4], r3[4];
  float* R = Gm + ((size_t)b * TQ + t) * TQ;
  const float cg = cgp[0], cb = cbp[0];
  for (int i = tid; i < t; i += 256) row[i] = R[i];
  __syncthreads();
  float m = -3e38f;
  for (int i = tid; i < t; i += 256) m = fmaxf(m, row[i]);
#pragma unroll
  for (int k = 1; k < 64; k <<= 1) m = fmaxf(m, __shfl_xor(m, k));
  if (lane == 0) r1[wv] = m;
  __syncthreads();
  m = fmaxf(fmaxf(r1[0], r1[1]), fmaxf(r1[2], r1[3]));
  float s = 0.f, sck = 0.f;
  for (int i = tid; i < t; i += 256) {
    const float r = row[i];
    const float e = __expf(r - m);
    const float ck = 1.f / (1.f + __expf(-(r * cg + cb)));
    row[i] = e; s += e; sck += e * ck;
  }
#pragma unroll
  for (int k = 1; k < 64; k <<= 1) { s += __shfl_xor(s, k); sck += __shfl_xor(sck, k); }
  if (lane == 0) { r2[wv] = s; r3[wv] = sck; }
  __syncthreads();
  s = r2[0] + r2[1] + r2[2] + r2[3];
  sck = r3[0] + r3[1] + r3[2] + r3[3];
  const float inv = 1.f / s;
  for (int i = tid; i < t; i += 256) R[i] = row[i] * inv;
  if (tid == 0) Sv[(size_t)b * TQ + t] = sck * inv;
}

// ---------------- K3: persistent recurrence, SINGLE sync hop per step ----------------
// 8 groups (4 batches each) x 64 WGs x 256 thr. WG owns 32 z-cols (weights in
// regs) + 4 key components (Mk slice in LDS). Per step each WG publishes
// {h_t (8 units), A_t (4 comps)} under ONE flag; consumers compute g_t
// redundantly from staged h (cheap 512-MAC dot), so the key_r broadcast hop
// is eliminated: z = h.Wh + g*(A.Wx + S*Wx[256]).
__global__ void __launch_bounds__(NTHR, 2) esbn_scan(
    const float* __restrict__ Wx, const float* __restrict__ Wh,
    const float* __restrict__ bl, const float* __restrict__ Wk,
    const float* __restrict__ bk, const float* __restrict__ Wg,
    const float* __restrict__ bgp, const float* __restrict__ Wmat,
    const float* __restrict__ Sv, float* buf, int* flagsX, int* flagsY,
    float* __restrict__ out) {
  (void)flagsY;
  __shared__ __align__(16) float st[NBG * SROW];     // [h | A | S] per local batch
  __shared__ __align__(16) float wrow[NBG * TQ];     // softmax row t
  __shared__ __align__(16) float Mk_s[16 * 520];     // [b][kl][tau] WG-local key mem
  __shared__ __align__(16) float wkey_s[4 * 520];
  __shared__ float wgv[HQ];
  __shared__ __align__(16) float zred[4 * 8 * 4 * 4];
  __shared__ float c_s[NBG * 8];
  __shared__ float gg_s[NBG];
  __shared__ float bl_s[32];
  __shared__ float bk_s[4];
  __shared__ float bg_s;

  const int tid = threadIdx.x;
  const int wg = blockIdx.x & 63;
  const int grp = blockIdx.x >> 6;   // 0..7
  const int b0 = grp * NBG;
  const int dc = tid >> 3;   // d-chunk 0..31
  const int cg = tid & 7;    // col group (4 cols)

  int colg[4];
#pragma unroll
  for (int j = 0; j < 4; ++j) {
    const int c = cg * 4 + j;
    colg[j] = (c >> 3) * HQ + wg * 8 + (c & 7);
  }
  f32x4 wh[16], wxr[8], wxl;
#pragma unroll
  for (int i = 0; i < 16; ++i) {
    const int d = (i << 5) + dc;
    wh[i].x = Wh[(size_t)d * G4 + colg[0]];
    wh[i].y = Wh[(size_t)d * G4 + colg[1]];
    wh[i].z = Wh[(size_t)d * G4 + colg[2]];
    wh[i].w = Wh[(size_t)d * G4 + colg[3]];
  }
#pragma unroll
  for (int i = 0; i < 8; ++i) {
    const int d = (i << 5) + dc;
    wxr[i].x = Wx[(size_t)d * G4 + colg[0]];
    wxr[i].y = Wx[(size_t)d * G4 + colg[1]];
    wxr[i].z = Wx[(size_t)d * G4 + colg[2]];
    wxr[i].w = Wx[(size_t)d * G4 + colg[3]];
  }
  wxl.x = wxl.y = wxl.z = wxl.w = 0.f;
  if (dc == 0) {
    wxl.x = Wx[(size_t)256 * G4 + colg[0]];
    wxl.y = Wx[(size_t)256 * G4 + colg[1]];
    wxl.z = Wx[(size_t)256 * G4 + colg[2]];
    wxl.w = Wx[(size_t)256 * G4 + colg[3]];
  }
  for (int i = tid; i < NBG * SROW; i += NTHR) st[i] = 0.f;
  for (int i = tid; i < 16 * 520; i += NTHR) Mk_s[i] = 0.f;
  for (int i = tid; i < 4 * 520; i += NTHR) {
    const int kl = i / 520, u = i - kl * 520;
    wkey_s[i] = (u < HQ) ? Wk[(size_t)u * KQ + wg * 4 + kl] : 0.f;
  }
  for (int i = tid; i < HQ; i += NTHR) wgv[i] = Wg[i];
  if (tid < 32) bl_s[tid] = bl[(tid >> 3) * HQ + wg * 8 + (tid & 7)];
  if (tid < 4) bk_s[tid] = bk[wg * 4 + tid];
  if (tid == 0) bg_s = bgp[0];
  if (tid < NBG * 8) c_s[tid] = 0.f;
  __syncthreads();

  int* f = flagsX + grp * 64;
  const int yb = tid >> 6;          // batch 0..3 (wave)
  const int ykl = (tid >> 4) & 3;   // key lane 0..3
  const int ytc = tid & 15;         // tau/u chunk 0..15
  const int lt = tid & 63;

  // staging geometry: 3 f32x4 per thread covering h (128 f4) + A (64 f4) / batch
  const int i0 = tid, i1 = tid + 256, i2 = tid + 512;
  const int sb0 = i0 / 192, so0 = i0 - sb0 * 192;
  const int sb1 = i1 / 192, so1 = i1 - sb1 * 192;
  const int sb2 = i2 / 192, so2 = i2 - sb2 * 192;
  const int sj0 = sb0 * SROW + ((so0 < 128) ? (so0 << 2) : (512 + ((so0 - 128) << 2)));
  const int sj1 = sb1 * SROW + ((so1 < 128) ? (so1 << 2) : (512 + ((so1 - 128) << 2)));
  const int sj2 = sb2 * SROW + ((so2 < 128) ? (so2 << 2) : (512 + ((so2 - 128) << 2)));

  for (int t = 0; t < TQ; ++t) {
    const int p = t & 1, pn = p ^ 1;
    // prefetch softmax row t into regs (flag-independent; consumed post-LSTM;
    // latency hides under the poll). No (u<t) mask needed: Mk tail is zero.
    float wv8[8];
    const bool rowv = (t >= 1) && (t < TQ - 1);
    if (rowv) {
      const float* wr = Wmat + ((size_t)(b0 + yb) * TQ + t) * TQ + lt;
#pragma unroll
      for (int k = 0; k < 8; ++k) wv8[k] = wr[k << 6];
    }
    if (t > 0) {
      wg_wait(f, t);   // h_{t-1} + A_{t-1} published by all 64 WGs
      float* base = buf + (size_t)(p * BQ + b0) * SROW;
      f32x4 v0, v1, v2;
      const float* q0 = base + sj0;
      const float* q1 = base + sj1;
      const float* q2 = base + sj2;
      asm volatile("global_load_dwordx4 %0, %1, off sc0 sc1" : "=v"(v0) : "v"(q0));
      asm volatile("global_load_dwordx4 %0, %1, off sc0 sc1" : "=v"(v1) : "v"(q1));
      asm volatile("global_load_dwordx4 %0, %1, off sc0 sc1" : "=v"(v2) : "v"(q2));
      float sv = 0.f;
      if (tid < 4) sv = Sv[(size_t)(b0 + tid) * TQ + (t - 1)];
      asm volatile("s_waitcnt vmcnt(0)" : "+v"(v0), "+v"(v1), "+v"(v2) : : "memory");
      *(f32x4*)&st[sj0] = v0;
      *(f32x4*)&st[sj1] = v1;
      *(f32x4*)&st[sj2] = v2;
      if (tid < 4) st[tid * SROW + 768] = sv;
    }
    __syncthreads();   // st (h, A, S) ready
    // g_{t-1} = sigmoid(h_{t-1} . Wg + bg), one wave per batch (redundant per WG)
    {
      float a = 0.f;
#pragma unroll
      for (int k = 0; k < 8; ++k) {
        const int u = lt + (k << 6);
        a += st[yb * SROW + u] * wgv[u];
      }
#pragma unroll
      for (int m = 1; m <= 32; m <<= 1) a += __shfl_xor(a, m);
      if (lt == 0) gg_s[yb] = sigm(a + bg_s);
    }
    // z = h-part + g * (A.Wx + S*Wx[256])
    f32x4 acc[NBG], pk[NBG];
#pragma unroll
    for (int b = 0; b < NBG; ++b) {
      acc[b].x = acc[b].y = acc[b].z = acc[b].w = 0.f;
      pk[b].x = pk[b].y = pk[b].z = pk[b].w = 0.f;
    }
#pragma unroll
    for (int i = 0; i < 16; ++i) {
      const f32x4 w = wh[i];
      const int d = (i << 5) + dc;
#pragma unroll
      for (int b = 0; b < NBG; ++b) acc[b] += st[b * SROW + d] * w;
    }
#pragma unroll
    for (int i = 0; i < 8; ++i) {
      const f32x4 w = wxr[i];
      const int d = 512 + (i << 5) + dc;
#pragma unroll
      for (int b = 0; b < NBG; ++b) pk[b] += st[b * SROW + d] * w;
    }
    if (dc == 0) {
#pragma unroll
      for (int b = 0; b < NBG; ++b) pk[b] += st[b * SROW + 768] * wxl;
    }
    __syncthreads();   // gg_s ready
#pragma unroll
    for (int b = 0; b < NBG; ++b) {
      const float g = gg_s[b];
      acc[b].x += g * pk[b].x; acc[b].y += g * pk[b].y;
      acc[b].z += g * pk[b].z; acc[b].w += g * pk[b].w;
    }
#pragma unroll
    for (int m = 8; m <= 32; m <<= 1) {
#pragma unroll
      for (int b = 0; b < NBG; ++b) {
        acc[b].x += __shfl_xor(acc[b].x, m);
        acc[b].y += __shfl_xor(acc[b].y, m);
        acc[b].z += __shfl_xor(acc[b].z, m);
        acc[b].w += __shfl_xor(acc[b].w, m);
      }
    }
    if (lt < 8) {
      const int wv = tid >> 6;
#pragma unroll
      for (int b = 0; b < NBG; ++b)
        *(f32x4*)&zred[((wv * 8 + lt) * 4 + b) * 4] = acc[b];
    }
    __syncthreads();
    if (tid < 32) {   // LSTM pointwise: thread = (b,u)
      const int b = tid >> 3, u = tid & 7;
      float zg[4];
#pragma unroll
      for (int g = 0; g < 4; ++g) {
        const int cgi = g * 2 + (u >> 2), comp = u & 3;
        float z = bl_s[g * 8 + u];
#pragma unroll
        for (int wv = 0; wv < 4; ++wv) z += zred[((wv * 8 + cgi) * 4 + b) * 4 + comp];
        zg[g] = z;
      }
      const float gi = sigm(zg[0]);
      const float gf = sigm(zg[1]);
      const float go = sigm(zg[3]);
      const float cn = gf * c_s[tid] + gi * tanhf(zg[2]);
      const float hv = go * tanhf(cn);
      c_s[tid] = cn;
      if (t == TQ - 1) out[(size_t)(b0 + b) * HQ + wg * 8 + u] = hv;
      else st_agent(buf + (size_t)(pn * BQ + b0 + b) * SROW + wg * 8 + u, hv);
    }
    if (t == TQ - 1) break;
    // A-producer: key_w_{t-1} -> Mk_s[t-1]; A_t = sum_tau w_t[tau]*Mk[tau];
    // publish raw A_t (same flag as h_t). All LDS deps are same-wave (in-order DS).
    if (t >= 1) {
#pragma unroll
      for (int k = 0; k < 8; ++k) wrow[yb * TQ + lt + (k << 6)] = wv8[k];
      float kw = 0.f;
      const float* hrow = &st[yb * SROW];
      const float* wkr = &wkey_s[ykl * 520];
#pragma unroll
      for (int j = 0; j < 32; ++j) {
        const int u = ytc + (j << 4);
        kw += hrow[u] * wkr[u];
      }
      kw += __shfl_xor(kw, 1);
      kw += __shfl_xor(kw, 2);
      kw += __shfl_xor(kw, 4);
      kw += __shfl_xor(kw, 8);
      if (ytc == 0) Mk_s[(yb * 4 + ykl) * 520 + (t - 1)] = kw + bk_s[ykl];
      float accA = 0.f;
      const float* mk = &Mk_s[(yb * 4 + ykl) * 520];
      const float* wb = &wrow[yb * TQ];
#pragma unroll
      for (int j = 0; j < 32; ++j) {
        const int u = ytc + (j << 4);
        accA += wb[u] * mk[u];
      }
      accA += __shfl_xor(accA, 1);
      accA += __shfl_xor(accA, 2);
      accA += __shfl_xor(accA, 4);
      accA += __shfl_xor(accA, 8);
      if (ytc == 0)
        st_agent(buf + (size_t)(pn * BQ + b0 + yb) * SROW + 512 + wg * 4 + ykl, accA);
    }
    wg_signal(&f[wg], t + 1);
  }
}

extern "C" void kernel_launch(void* const* d_in, const int* in_sizes, int n_in,
                              void* d_out, int out_size, void* d_ws, size_t ws_size,
                              hipStream_t stream) {
  (void)in_sizes; (void)n_in; (void)out_size; (void)ws_size;
  const float* X  = (const float*)d_in[0];
  const float* Wx = (const float*)d_in[1];
  const float* Wh = (const float*)d_in[2];
  const float* bl = (const float*)d_in[3];
  const float* Wk = (const float*)d_in[4];
  const float* bk = (const float*)d_in[5];
  const float* Wg = (const float*)d_in[6];
  const float* bg = (const float*)d_in[7];
  const float* cg = (const float*)d_in[8];
  const float* cb = (const float*)d_in[9];
  float* out = (float*)d_out;
  float* ws = (float*)d_ws;

  float* Gm = ws;                              // 32*512*512 = 8,388,608 f
  float* Sv = ws + (size_t)8388608;            // 32*512 = 16,384 f
  float* buf = ws + (size_t)8404992;           // 2*32*772 = 49,408 f
  int* flagsX = (int*)(ws + (size_t)8454400);  // 512 + 512 ints
  int* flagsY = flagsX + 512;

  // zero Sv | state double-buffer | flags (one contiguous region)
  hipMemsetAsync(Sv, 0, (size_t)(16384 + 49408 + 1024) * 4, stream);
  gram_k<<<dim3(36, BQ), dim3(256), 0, stream>>>(X, Gm);
  smax_k<<<dim3(TQ - 1, BQ), dim3(256), 0, stream>>>(Gm, Sv, cg, cb);

  void* args[] = {(void*)&Wx, (void*)&Wh, (void*)&bl, (void*)&Wk, (void*)&bk,
                  (void*)&Wg, (void*)&bg, (void*)&Gm, (void*)&Sv,
                  (void*)&buf, (void*)&flagsX, (void*)&flagsY, (void*)&out};
  hipError_t e = hipLaunchCooperativeKernel((const void*)esbn_scan, dim3(NWG),
                                            dim3(NTHR), args, 0, stream);
  if (e != hipSuccess) {
    esbn_scan<<<dim3(NWG), dim3(NTHR), 0, stream>>>(Wx, Wh, bl, Wk, bk, Wg, bg,
                                                    Gm, Sv, buf, flagsX,
                                                    flagsY, out);
  }
}

// Round 3
// 4686.173 us; speedup vs baseline: 1.0953x; 1.0953x over previous
//
#include <hip/hip_runtime.h>
#include <math.h>

#define BQ 32
#define TQ 512
#define DQ 768
#define KQ 256
#define HQ 512
#define G4 2048
#define SROW 772   // state row: h[0:512) | A[512:768) | S at [768] | pad to 772
#define NWG 512    // 8 groups x 64 WGs
#define NTHR 256
#define NBG 4      // batches per group

typedef float f32x4 __attribute__((ext_vector_type(4)));

// Device (agent) scope = sc1 only on gfx94x/gfx950: coherent across XCDs,
// cheaper than system scope (sc0 sc1) which orders against the host path.
__device__ __forceinline__ void waitcnt0() {
  asm volatile("s_waitcnt vmcnt(0) lgkmcnt(0)" ::: "memory");
}
__device__ __forceinline__ void st_dev(float* p, float v) {
  asm volatile("global_store_dword %0, %1, off sc1" :: "v"(p), "v"(v) : "memory");
}
__device__ __forceinline__ int ld_flag(const int* p) {
  int v;
  asm volatile("global_load_dword %0, %1, off sc1\ns_waitcnt vmcnt(0)"
               : "=v"(v) : "v"(p) : "memory");
  return v;
}
// single-wave poll: waves 1-3 park at the barrier (4x less poll traffic)
__device__ __forceinline__ void wg_wait(const int* flags, int target) {
  if (threadIdx.x < 64) {
    for (;;) {
      int v = ld_flag(flags + threadIdx.x);
      if (__all(v >= target)) break;
      __builtin_amdgcn_s_sleep(2);
    }
  }
  __syncthreads();
}
__device__ __forceinline__ void wg_signal(int* flag, int val) {
  waitcnt0();
  __syncthreads();
  if (threadIdx.x == 0)
    asm volatile("global_store_dword %0, %1, off sc1" :: "v"(flag), "v"(val) : "memory");
}
__device__ __forceinline__ float sigm(float x) { return 1.f / (1.f + __expf(-x)); }

// ---------------- P1: Gram matrix G[b][t][tau] = x_t . x_tau ----------------
__global__ void __launch_bounds__(256) gram_k(const float* __restrict__ X,
                                              float* __restrict__ Gm) {
  __shared__ __align__(16) float As[64 * 33];
  __shared__ __align__(16) float Bs[64 * 33];
  const int bid = blockIdx.x;
  const int b = blockIdx.y;
  int I = 0, base = 0;
  while (base + I + 1 <= bid) { base += I + 1; ++I; }
  const int J = bid - base;
  const int t0 = I * 64, u0 = J * 64;
  const float* Xb = X + (size_t)b * TQ * DQ;
  const int ty = threadIdx.x >> 4, tx = threadIdx.x & 15;
  const int sc = threadIdx.x & 31, sr = threadIdx.x >> 5;
  float acc[4][4];
#pragma unroll
  for (int i = 0; i < 4; ++i)
#pragma unroll
    for (int j = 0; j < 4; ++j) acc[i][j] = 0.f;
  for (int k0 = 0; k0 < DQ; k0 += 32) {
#pragma unroll
    for (int rr = 0; rr < 8; ++rr) {
      const int r = rr * 8 + sr;
      As[r * 33 + sc] = Xb[(size_t)(t0 + r) * DQ + k0 + sc];
      Bs[r * 33 + sc] = Xb[(size_t)(u0 + r) * DQ + k0 + sc];
    }
    __syncthreads();
#pragma unroll
    for (int k = 0; k < 32; ++k) {
      float av[4], bv[4];
#pragma unroll
      for (int i = 0; i < 4; ++i) av[i] = As[(ty * 4 + i) * 33 + k];
#pragma unroll
      for (int j = 0; j < 4; ++j) bv[j] = Bs[(tx * 4 + j) * 33 + k];
#pragma unroll
      for (int i = 0; i < 4; ++i)
#pragma unroll
        for (int j = 0; j < 4; ++j) acc[i][j] += av[i] * bv[j];
    }
    __syncthreads();
  }
  float* gb = Gm + (size_t)b * TQ * TQ;
#pragma unroll
  for (int i = 0; i < 4; ++i) {
    f32x4 o;
    o.x = acc[i][0]; o.y = acc[i][1]; o.z = acc[i][2]; o.w = acc[i][3];
    *(f32x4*)&gb[(size_t)(t0 + ty * 4 + i) * TQ + u0 + tx * 4] = o;
  }
}

// ---------------- P2: row softmax (tau < t) in place + S[b][t] ----------------
__global__ void __launch_bounds__(256) smax_k(float* __restrict__ Gm,
                                              float* __restrict__ Sv,
                                              const float* __restrict__ cgp,
                                              const float* __restrict__ cbp) {
  const int t = blockIdx.x + 1;   // 1..511
  const int b = blockIdx.y;
  const int tid = threadIdx.x;
  const int lane = tid & 63;
  const int wv = tid >> 6;
  __shared__ float row[TQ];
  __shared__ float r1[4], r2[4], r3[4];
  float* R = Gm + ((size_t)b * TQ + t) * TQ;
  const float cg = cgp[0], cb = cbp[0];
  for (int i = tid; i < t; i += 256) row[i] = R[i];
  __syncthreads();
  float m = -3e38f;
  for (int i = tid; i < t; i += 256) m = fmaxf(m, row[i]);
#pragma unroll
  for (int k = 1; k < 64; k <<= 1) m = fmaxf(m, __shfl_xor(m, k));
  if (lane == 0) r1[wv] = m;
  __syncthreads();
  m = fmaxf(fmaxf(r1[0], r1[1]), fmaxf(r1[2], r1[3]));
  float s = 0.f, sck = 0.f;
  for (int i = tid; i < t; i += 256) {
    const float r = row[i];
    const float e = __expf(r - m);
    const float ck = 1.f / (1.f + __expf(-(r * cg + cb)));
    row[i] = e; s += e; sck += e * ck;
  }
#pragma unroll
  for (int k = 1; k < 64; k <<= 1) { s += __shfl_xor(s, k); sck += __shfl_xor(sck, k); }
  if (lane == 0) { r2[wv] = s; r3[wv] = sck; }
  __syncthreads();
  s = r2[0] + r2[1] + r2[2] + r2[3];
  sck = r3[0] + r3[1] + r3[2] + r3[3];
  const float inv = 1.f / s;
  for (int i = tid; i < t; i += 256) R[i] = row[i] * inv;
  if (tid == 0) Sv[(size_t)b * TQ + t] = sck * inv;
}

// ---------------- K3: persistent recurrence, single sync hop per step --------
// 8 groups (4 batches each) x 64 WGs x 256 thr. WG owns 32 z-cols (weights in
// regs) + 4 key components (Mk slice in LDS). Per step each WG publishes
// {h_t (8 units), A_t (4 comps)} under ONE flag; consumers compute g_t
// redundantly from staged h. All cross-WG traffic at DEVICE scope (sc1).
__global__ void __launch_bounds__(NTHR, 2) esbn_scan(
    const float* __restrict__ Wx, const float* __restrict__ Wh,
    const float* __restrict__ bl, const float* __restrict__ Wk,
    const float* __restrict__ bk, const float* __restrict__ Wg,
    const float* __restrict__ bgp, const float* __restrict__ Wmat,
    const float* __restrict__ Sv, float* buf, int* flagsX, int* flagsY,
    float* __restrict__ out) {
  (void)flagsY;
  __shared__ __align__(16) float st[NBG * SROW];     // [h | A | S] per local batch
  __shared__ __align__(16) float wrow[NBG * TQ];     // softmax row t
  __shared__ __align__(16) float Mk_s[16 * 520];     // [b][kl][tau] WG-local key mem
  __shared__ __align__(16) float wkey_s[4 * 520];
  __shared__ float wgv[HQ];
  __shared__ __align__(16) float zred[4 * 8 * 4 * 4];
  __shared__ float c_s[NBG * 8];
  __shared__ float gg_s[NBG];
  __shared__ float bl_s[32];
  __shared__ float bk_s[4];
  __shared__ float bg_s;

  const int tid = threadIdx.x;
  const int wg = blockIdx.x & 63;
  const int grp = blockIdx.x >> 6;   // 0..7
  const int b0 = grp * NBG;
  const int dc = tid >> 3;   // d-chunk 0..31
  const int cg = tid & 7;    // col group (4 cols)

  int colg[4];
#pragma unroll
  for (int j = 0; j < 4; ++j) {
    const int c = cg * 4 + j;
    colg[j] = (c >> 3) * HQ + wg * 8 + (c & 7);
  }
  f32x4 wh[16], wxr[8], wxl;
#pragma unroll
  for (int i = 0; i < 16; ++i) {
    const int d = (i << 5) + dc;
    wh[i].x = Wh[(size_t)d * G4 + colg[0]];
    wh[i].y = Wh[(size_t)d * G4 + colg[1]];
    wh[i].z = Wh[(size_t)d * G4 + colg[2]];
    wh[i].w = Wh[(size_t)d * G4 + colg[3]];
  }
#pragma unroll
  for (int i = 0; i < 8; ++i) {
    const int d = (i << 5) + dc;
    wxr[i].x = Wx[(size_t)d * G4 + colg[0]];
    wxr[i].y = Wx[(size_t)d * G4 + colg[1]];
    wxr[i].z = Wx[(size_t)d * G4 + colg[2]];
    wxr[i].w = Wx[(size_t)d * G4 + colg[3]];
  }
  wxl.x = wxl.y = wxl.z = wxl.w = 0.f;
  if (dc == 0) {
    wxl.x = Wx[(size_t)256 * G4 + colg[0]];
    wxl.y = Wx[(size_t)256 * G4 + colg[1]];
    wxl.z = Wx[(size_t)256 * G4 + colg[2]];
    wxl.w = Wx[(size_t)256 * G4 + colg[3]];
  }
  for (int i = tid; i < NBG * SROW; i += NTHR) st[i] = 0.f;
  for (int i = tid; i < 16 * 520; i += NTHR) Mk_s[i] = 0.f;
  for (int i = tid; i < 4 * 520; i += NTHR) {
    const int kl = i / 520, u = i - kl * 520;
    wkey_s[i] = (u < HQ) ? Wk[(size_t)u * KQ + wg * 4 + kl] : 0.f;
  }
  for (int i = tid; i < HQ; i += NTHR) wgv[i] = Wg[i];
  if (tid < 32) bl_s[tid] = bl[(tid >> 3) * HQ + wg * 8 + (tid & 7)];
  if (tid < 4) bk_s[tid] = bk[wg * 4 + tid];
  if (tid == 0) bg_s = bgp[0];
  if (tid < NBG * 8) c_s[tid] = 0.f;
  __syncthreads();

  int* f = flagsX + grp * 64;
  const int yb = tid >> 6;          // batch 0..3 (wave)
  const int ykl = (tid >> 4) & 3;   // key lane 0..3
  const int ytc = tid & 15;         // tau/u chunk 0..15
  const int lt = tid & 63;

  // staging geometry: 3 f32x4 per thread covering h (128 f4) + A (64 f4) / batch
  const int i0 = tid, i1 = tid + 256, i2 = tid + 512;
  const int sb0 = i0 / 192, so0 = i0 - sb0 * 192;
  const int sb1 = i1 / 192, so1 = i1 - sb1 * 192;
  const int sb2 = i2 / 192, so2 = i2 - sb2 * 192;
  const int sj0 = sb0 * SROW + ((so0 < 128) ? (so0 << 2) : (512 + ((so0 - 128) << 2)));
  const int sj1 = sb1 * SROW + ((so1 < 128) ? (so1 << 2) : (512 + ((so1 - 128) << 2)));
  const int sj2 = sb2 * SROW + ((so2 < 128) ? (so2 << 2) : (512 + ((so2 - 128) << 2)));

  for (int t = 0; t < TQ; ++t) {
    const int p = t & 1, pn = p ^ 1;
    // prefetch softmax row t into regs (flag-independent; consumed post-LSTM)
    float wv8[8];
    const bool rowv = (t >= 1) && (t < TQ - 1);
    if (rowv) {
      const float* wr = Wmat + ((size_t)(b0 + yb) * TQ + t) * TQ + lt;
#pragma unroll
      for (int k = 0; k < 8; ++k) wv8[k] = wr[k << 6];
    }
    if (t > 0) {
      wg_wait(f, t);   // h_{t-1} + A_{t-1} published by all 64 WGs
      float* base = buf + (size_t)(p * BQ + b0) * SROW;
      f32x4 v0, v1, v2;
      const float* q0 = base + sj0;
      const float* q1 = base + sj1;
      const float* q2 = base + sj2;
      asm volatile("global_load_dwordx4 %0, %1, off sc1" : "=v"(v0) : "v"(q0));
      asm volatile("global_load_dwordx4 %0, %1, off sc1" : "=v"(v1) : "v"(q1));
      asm volatile("global_load_dwordx4 %0, %1, off sc1" : "=v"(v2) : "v"(q2));
      float sv = 0.f;
      if (tid < 4) sv = Sv[(size_t)(b0 + tid) * TQ + (t - 1)];
      asm volatile("s_waitcnt vmcnt(0)" : "+v"(v0), "+v"(v1), "+v"(v2) : : "memory");
      *(f32x4*)&st[sj0] = v0;
      *(f32x4*)&st[sj1] = v1;
      *(f32x4*)&st[sj2] = v2;
      if (tid < 4) st[tid * SROW + 768] = sv;
    }
    __syncthreads();   // st (h, A, S) ready
    // g_{t-1} = sigmoid(h_{t-1} . Wg + bg), one wave per batch (redundant per WG)
    {
      float a = 0.f;
#pragma unroll
      for (int k = 0; k < 8; ++k) {
        const int u = lt + (k << 6);
        a += st[yb * SROW + u] * wgv[u];
      }
#pragma unroll
      for (int m = 1; m <= 32; m <<= 1) a += __shfl_xor(a, m);
      if (lt == 0) gg_s[yb] = sigm(a + bg_s);
    }
    // z = h-part + g * (A.Wx + S*Wx[256])
    f32x4 acc[NBG], pk[NBG];
#pragma unroll
    for (int b = 0; b < NBG; ++b) {
      acc[b].x = acc[b].y = acc[b].z = acc[b].w = 0.f;
      pk[b].x = pk[b].y = pk[b].z = pk[b].w = 0.f;
    }
#pragma unroll
    for (int i = 0; i < 16; ++i) {
      const f32x4 w = wh[i];
      const int d = (i << 5) + dc;
#pragma unroll
      for (int b = 0; b < NBG; ++b) acc[b] += st[b * SROW + d] * w;
    }
#pragma unroll
    for (int i = 0; i < 8; ++i) {
      const f32x4 w = wxr[i];
      const int d = 512 + (i << 5) + dc;
#pragma unroll
      for (int b = 0; b < NBG; ++b) pk[b] += st[b * SROW + d] * w;
    }
    if (dc == 0) {
#pragma unroll
      for (int b = 0; b < NBG; ++b) pk[b] += st[b * SROW + 768] * wxl;
    }
    __syncthreads();   // gg_s ready
#pragma unroll
    for (int b = 0; b < NBG; ++b) {
      const float g = gg_s[b];
      acc[b].x += g * pk[b].x; acc[b].y += g * pk[b].y;
      acc[b].z += g * pk[b].z; acc[b].w += g * pk[b].w;
    }
#pragma unroll
    for (int m = 8; m <= 32; m <<= 1) {
#pragma unroll
      for (int b = 0; b < NBG; ++b) {
        acc[b].x += __shfl_xor(acc[b].x, m);
        acc[b].y += __shfl_xor(acc[b].y, m);
        acc[b].z += __shfl_xor(acc[b].z, m);
        acc[b].w += __shfl_xor(acc[b].w, m);
      }
    }
    if (lt < 8) {
      const int wv = tid >> 6;
#pragma unroll
      for (int b = 0; b < NBG; ++b)
        *(f32x4*)&zred[((wv * 8 + lt) * 4 + b) * 4] = acc[b];
    }
    __syncthreads();
    if (tid < 32) {   // LSTM pointwise: thread = (b,u)
      const int b = tid >> 3, u = tid & 7;
      float zg[4];
#pragma unroll
      for (int g = 0; g < 4; ++g) {
        const int cgi = g * 2 + (u >> 2), comp = u & 3;
        float z = bl_s[g * 8 + u];
#pragma unroll
        for (int wv = 0; wv < 4; ++wv) z += zred[((wv * 8 + cgi) * 4 + b) * 4 + comp];
        zg[g] = z;
      }
      const float gi = sigm(zg[0]);
      const float gf = sigm(zg[1]);
      const float go = sigm(zg[3]);
      const float cn = gf * c_s[tid] + gi * tanhf(zg[2]);
      const float hv = go * tanhf(cn);
      c_s[tid] = cn;
      if (t == TQ - 1) out[(size_t)(b0 + b) * HQ + wg * 8 + u] = hv;
      else st_dev(buf + (size_t)(pn * BQ + b0 + b) * SROW + wg * 8 + u, hv);
    }
    if (t == TQ - 1) break;
    // A-producer: key_w_{t-1} -> Mk_s[t-1]; A_t = sum_tau w_t[tau]*Mk[tau];
    // publish raw A_t (same flag as h_t).
    if (t >= 1) {
#pragma unroll
      for (int k = 0; k < 8; ++k) wrow[yb * TQ + lt + (k << 6)] = wv8[k];
      float kw = 0.f;
      const float* hrow = &st[yb * SROW];
      const float* wkr = &wkey_s[ykl * 520];
#pragma unroll
      for (int j = 0; j < 32; ++j) {
        const int u = ytc + (j << 4);
        kw += hrow[u] * wkr[u];
      }
      kw += __shfl_xor(kw, 1);
      kw += __shfl_xor(kw, 2);
      kw += __shfl_xor(kw, 4);
      kw += __shfl_xor(kw, 8);
      if (ytc == 0) Mk_s[(yb * 4 + ykl) * 520 + (t - 1)] = kw + bk_s[ykl];
      float accA = 0.f;
      const float* mk = &Mk_s[(yb * 4 + ykl) * 520];
      const float* wb = &wrow[yb * TQ];
#pragma unroll
      for (int j = 0; j < 32; ++j) {
        const int u = ytc + (j << 4);
        accA += wb[u] * mk[u];
      }
      accA += __shfl_xor(accA, 1);
      accA += __shfl_xor(accA, 2);
      accA += __shfl_xor(accA, 4);
      accA += __shfl_xor(accA, 8);
      if (ytc == 0)
        st_dev(buf + (size_t)(pn * BQ + b0 + yb) * SROW + 512 + wg * 4 + ykl, accA);
    }
    wg_signal(&f[wg], t + 1);
  }
}

extern "C" void kernel_launch(void* const* d_in, const int* in_sizes, int n_in,
                              void* d_out, int out_size, void* d_ws, size_t ws_size,
                              hipStream_t stream) {
  (void)in_sizes; (void)n_in; (void)out_size; (void)ws_size;
  const float* X  = (const float*)d_in[0];
  const float* Wx = (const float*)d_in[1];
  const float* Wh = (const float*)d_in[2];
  const float* bl = (const float*)d_in[3];
  const float* Wk = (const float*)d_in[4];
  const float* bk = (const float*)d_in[5];
  const float* Wg = (const float*)d_in[6];
  const float* bg = (const float*)d_in[7];
  const float* cg = (const float*)d_in[8];
  const float* cb = (const float*)d_in[9];
  float* out = (float*)d_out;
  float* ws = (float*)d_ws;

  float* Gm = ws;                              // 32*512*512 = 8,388,608 f
  float* Sv = ws + (size_t)8388608;            // 32*512 = 16,384 f
  float* buf = ws + (size_t)8404992;           // 2*32*772 = 49,408 f
  int* flagsX = (int*)(ws + (size_t)8454400);  // 512 + 512 ints
  int* flagsY = flagsX + 512;

  // zero Sv | state double-buffer | flags (one contiguous region)
  hipMemsetAsync(Sv, 0, (size_t)(16384 + 49408 + 1024) * 4, stream);
  gram_k<<<dim3(36, BQ), dim3(256), 0, stream>>>(X, Gm);
  smax_k<<<dim3(TQ - 1, BQ), dim3(256), 0, stream>>>(Gm, Sv, cg, cb);

  void* args[] = {(void*)&Wx, (void*)&Wh, (void*)&bl, (void*)&Wk, (void*)&bk,
                  (void*)&Wg, (void*)&bg, (void*)&Gm, (void*)&Sv,
                  (void*)&buf, (void*)&flagsX, (void*)&flagsY, (void*)&out};
  hipError_t e = hipLaunchCooperativeKernel((const void*)esbn_scan, dim3(NWG),
                                            dim3(NTHR), args, 0, stream);
  if (e != hipSuccess) {
    esbn_scan<<<dim3(NWG), dim3(NTHR), 0, stream>>>(Wx, Wh, bl, Wk, bk, Wg, bg,
                                                    Gm, Sv, buf, flagsX,
                                                    flagsY, out);
  }
}

// Round 4
// 4645.679 us; speedup vs baseline: 1.1049x; 1.0087x over previous
//
#include <hip/hip_runtime.h>
#include <math.h>

#define BQ 32
#define TQ 512
#define DQ 768
#define KQ 256
#define HQ 512
#define G4 2048
#define BROW 768   // buf row: h[0:512) | A[512:768)
#define STP 772    // LDS state row stride (pad for banks)
#define NWG 512    // 8 groups x 64 WGs
#define NTHR 256
#define NBG 4      // batches per group

typedef float f32x4 __attribute__((ext_vector_type(4)));

// Device (agent) scope = sc1 on gfx950: coherent across XCDs.
__device__ __forceinline__ void waitcnt0() {
  asm volatile("s_waitcnt vmcnt(0) lgkmcnt(0)" ::: "memory");
}
__device__ __forceinline__ void st_dev(float* p, float v) {
  asm volatile("global_store_dword %0, %1, off sc1" :: "v"(p), "v"(v) : "memory");
}
__device__ __forceinline__ int ld_dev(const int* p) {
  int v;
  asm volatile("global_load_dword %0, %1, off sc1\ns_waitcnt vmcnt(0)"
               : "=v"(v) : "v"(p) : "memory");
  return v;
}
// one counter per group, own 128B line; wave0 polls one coalesced address
__device__ __forceinline__ void wg_wait_ctr(const int* ctr, int target) {
  if (threadIdx.x < 64) {
    while (ld_dev(ctr) < target) __builtin_amdgcn_s_sleep(1);
  }
  __syncthreads();
}
__device__ __forceinline__ void wg_signal_ctr(int* ctr) {
  waitcnt0();
  __syncthreads();
  if (threadIdx.x == 0) atomicAdd(ctr, 1);
}
__device__ __forceinline__ float sigm(float x) { return 1.f / (1.f + __expf(-x)); }

// ---------------- P1: Gram matrix G[b][t][tau] = x_t . x_tau ----------------
__global__ void __launch_bounds__(256) gram_k(const float* __restrict__ X,
                                              float* __restrict__ Gm) {
  __shared__ __align__(16) float As[64 * 33];
  __shared__ __align__(16) float Bs[64 * 33];
  const int bid = blockIdx.x;
  const int b = blockIdx.y;
  int I = 0, base = 0;
  while (base + I + 1 <= bid) { base += I + 1; ++I; }
  const int J = bid - base;
  const int t0 = I * 64, u0 = J * 64;
  const float* Xb = X + (size_t)b * TQ * DQ;
  const int ty = threadIdx.x >> 4, tx = threadIdx.x & 15;
  const int sc = threadIdx.x & 31, sr = threadIdx.x >> 5;
  float acc[4][4];
#pragma unroll
  for (int i = 0; i < 4; ++i)
#pragma unroll
    for (int j = 0; j < 4; ++j) acc[i][j] = 0.f;
  for (int k0 = 0; k0 < DQ; k0 += 32) {
#pragma unroll
    for (int rr = 0; rr < 8; ++rr) {
      const int r = rr * 8 + sr;
      As[r * 33 + sc] = Xb[(size_t)(t0 + r) * DQ + k0 + sc];
      Bs[r * 33 + sc] = Xb[(size_t)(u0 + r) * DQ + k0 + sc];
    }
    __syncthreads();
#pragma unroll
    for (int k = 0; k < 32; ++k) {
      float av[4], bv[4];
#pragma unroll
      for (int i = 0; i < 4; ++i) av[i] = As[(ty * 4 + i) * 33 + k];
#pragma unroll
      for (int j = 0; j < 4; ++j) bv[j] = Bs[(tx * 4 + j) * 33 + k];
#pragma unroll
      for (int i = 0; i < 4; ++i)
#pragma unroll
        for (int j = 0; j < 4; ++j) acc[i][j] += av[i] * bv[j];
    }
    __syncthreads();
  }
  float* gb = Gm + (size_t)b * TQ * TQ;
#pragma unroll
  for (int i = 0; i < 4; ++i) {
    f32x4 o;
    o.x = acc[i][0]; o.y = acc[i][1]; o.z = acc[i][2]; o.w = acc[i][3];
    *(f32x4*)&gb[(size_t)(t0 + ty * 4 + i) * TQ + u0 + tx * 4] = o;
  }
}

// ---------------- P2: row softmax (tau < t) in place + S[b][t] ----------------
__global__ void __launch_bounds__(256) smax_k(float* __restrict__ Gm,
                                              float* __restrict__ Sv,
                                              const float* __restrict__ cgp,
                                              const float* __restrict__ cbp) {
  const int t = blockIdx.x + 1;   // 1..511
  const int b = blockIdx.y;
  const int tid = threadIdx.x;
  const int lane = tid & 63;
  const int wv = tid >> 6;
  __shared__ float row[TQ];
  __shared__ float r1[4], r2[4], r3[4];
  float* R = Gm + ((size_t)b * TQ + t) * TQ;
  const float cg = cgp[0], cb = cbp[0];
  for (int i = tid; i < t; i += 256) row[i] = R[i];
  __syncthreads();
  float m = -3e38f;
  for (int i = tid; i < t; i += 256) m = fmaxf(m, row[i]);
#pragma unroll
  for (int k = 1; k < 64; k <<= 1) m = fmaxf(m, __shfl_xor(m, k));
  if (lane == 0) r1[wv] = m;
  __syncthreads();
  m = fmaxf(fmaxf(r1[0], r1[1]), fmaxf(r1[2], r1[3]));
  float s = 0.f, sck = 0.f;
  for (int i = tid; i < t; i += 256) {
    const float r = row[i];
    const float e = __expf(r - m);
    const float ck = 1.f / (1.f + __expf(-(r * cg + cb)));
    row[i] = e; s += e; sck += e * ck;
  }
#pragma unroll
  for (int k = 1; k < 64; k <<= 1) { s += __shfl_xor(s, k); sck += __shfl_xor(sck, k); }
  if (lane == 0) { r2[wv] = s; r3[wv] = sck; }
  __syncthreads();
  s = r2[0] + r2[1] + r2[2] + r2[3];
  sck = r3[0] + r3[1] + r3[2] + r3[3];
  const float inv = 1.f / s;
  for (int i = tid; i < t; i += 256) R[i] = row[i] * inv;
  if (tid == 0) Sv[(size_t)b * TQ + t] = sck * inv;
}

// ---------------- K3: persistent recurrence, atomic-counter sync -------------
// 8 groups (4 batches each) x 64 WGs x 256 thr. Per step each WG publishes
// {h_t (8 units), A_t (4 comps)} then atomicAdd(ctr); consumers poll ONE
// counter line (ctr >= 64*t) instead of 64 flags on 2 hot LLC lines.
// Sv preloaded to LDS; g computed per-wave (no cross-wave barrier).
__global__ void __launch_bounds__(NTHR, 2) esbn_scan(
    const float* __restrict__ Wx, const float* __restrict__ Wh,
    const float* __restrict__ bl, const float* __restrict__ Wk,
    const float* __restrict__ bk, const float* __restrict__ Wg,
    const float* __restrict__ bgp, const float* __restrict__ Wmat,
    const float* __restrict__ Sv, float* buf, int* ctrs,
    float* __restrict__ out) {
  __shared__ __align__(16) float st[NBG * STP];      // [h | A] per local batch
  __shared__ __align__(16) float wrow[NBG * TQ];     // softmax row t
  __shared__ __align__(16) float Mk_s[16 * 520];     // [b][kl][tau] WG-local key mem
  __shared__ __align__(16) float wkey_s[4 * 520];
  __shared__ __align__(16) float wgv[HQ];
  __shared__ __align__(16) float svl[NBG * TQ];      // Sv rows for this group
  __shared__ __align__(16) float zred[4 * 8 * 4 * 4];
  __shared__ float c_s[NBG * 8];
  __shared__ float bl_s[32];
  __shared__ float bk_s[4];
  __shared__ float bg_s;

  const int tid = threadIdx.x;
  const int wg = blockIdx.x & 63;
  const int grp = blockIdx.x >> 6;   // 0..7
  const int b0 = grp * NBG;
  const int dc = tid >> 3;   // d-chunk 0..31
  const int cg = tid & 7;    // col group (4 cols)

  int colg[4];
#pragma unroll
  for (int j = 0; j < 4; ++j) {
    const int c = cg * 4 + j;
    colg[j] = (c >> 3) * HQ + wg * 8 + (c & 7);
  }
  f32x4 wh[16], wxr[8], wxl;
#pragma unroll
  for (int i = 0; i < 16; ++i) {
    const int d = (i << 5) + dc;
    wh[i].x = Wh[(size_t)d * G4 + colg[0]];
    wh[i].y = Wh[(size_t)d * G4 + colg[1]];
    wh[i].z = Wh[(size_t)d * G4 + colg[2]];
    wh[i].w = Wh[(size_t)d * G4 + colg[3]];
  }
#pragma unroll
  for (int i = 0; i < 8; ++i) {
    const int d = (i << 5) + dc;
    wxr[i].x = Wx[(size_t)d * G4 + colg[0]];
    wxr[i].y = Wx[(size_t)d * G4 + colg[1]];
    wxr[i].z = Wx[(size_t)d * G4 + colg[2]];
    wxr[i].w = Wx[(size_t)d * G4 + colg[3]];
  }
  wxl.x = wxl.y = wxl.z = wxl.w = 0.f;
  if (dc == 0) {
    wxl.x = Wx[(size_t)256 * G4 + colg[0]];
    wxl.y = Wx[(size_t)256 * G4 + colg[1]];
    wxl.z = Wx[(size_t)256 * G4 + colg[2]];
    wxl.w = Wx[(size_t)256 * G4 + colg[3]];
  }
  for (int i = tid; i < NBG * STP; i += NTHR) st[i] = 0.f;
  for (int i = tid; i < 16 * 520; i += NTHR) Mk_s[i] = 0.f;
  for (int i = tid; i < 4 * 520; i += NTHR) {
    const int kl = i / 520, u = i - kl * 520;
    wkey_s[i] = (u < HQ) ? Wk[(size_t)u * KQ + wg * 4 + kl] : 0.f;
  }
  for (int i = tid; i < HQ; i += NTHR) wgv[i] = Wg[i];
  for (int i = tid; i < NBG * TQ; i += NTHR)
    svl[i] = Sv[(size_t)(b0 + (i >> 9)) * TQ + (i & 511)];
  if (tid < 32) bl_s[tid] = bl[(tid >> 3) * HQ + wg * 8 + (tid & 7)];
  if (tid < 4) bk_s[tid] = bk[wg * 4 + tid];
  if (tid == 0) bg_s = bgp[0];
  if (tid < NBG * 8) c_s[tid] = 0.f;
  __syncthreads();

  int* ctr = ctrs + grp * 32;        // own 128B line per group
  const int yb = tid >> 6;          // batch 0..3 (wave)
  const int ykl = (tid >> 4) & 3;   // key lane 0..3
  const int ytc = tid & 15;         // tau/u chunk 0..15
  const int lt = tid & 63;

  // staging: 3 dwordx4/thread over the 4x768 contiguous parity block
  int sgo[3], slo[3];
#pragma unroll
  for (int k = 0; k < 3; ++k) {
    const int c = tid + (k << 8);          // chunk 0..767
    const int b = c / 192, off = (c - b * 192) << 2;
    sgo[k] = (b << 9) + (b << 8) + off;    // b*768 + off
    slo[k] = b * STP + off;
  }

  for (int t = 0; t < TQ; ++t) {
    const int p = t & 1, pn = p ^ 1;
    // prefetch softmax row t into regs (flag-independent; consumed post-LSTM)
    float wv8[8];
    const bool rowv = (t >= 1) && (t < TQ - 1);
    if (rowv) {
      const float* wr = Wmat + ((size_t)(b0 + yb) * TQ + t) * TQ + lt;
#pragma unroll
      for (int k = 0; k < 8; ++k) wv8[k] = wr[k << 6];
    }
    if (t > 0) {
      wg_wait_ctr(ctr, 64 * t);   // all 64 WGs published step t-1
      const float* base = buf + (size_t)(p * BQ + b0) * BROW;
      f32x4 v0, v1, v2;
      const float* q0 = base + sgo[0];
      const float* q1 = base + sgo[1];
      const float* q2 = base + sgo[2];
      asm volatile("global_load_dwordx4 %0, %1, off sc1" : "=v"(v0) : "v"(q0));
      asm volatile("global_load_dwordx4 %0, %1, off sc1" : "=v"(v1) : "v"(q1));
      asm volatile("global_load_dwordx4 %0, %1, off sc1" : "=v"(v2) : "v"(q2));
      asm volatile("s_waitcnt vmcnt(0)" : "+v"(v0), "+v"(v1), "+v"(v2) : : "memory");
      *(f32x4*)&st[slo[0]] = v0;
      *(f32x4*)&st[slo[1]] = v1;
      *(f32x4*)&st[slo[2]] = v2;
    }
    __syncthreads();   // st (h, A) ready
    // g_{t-1}[0..3] per-wave: 16-lane sub-group per batch, broadcast in-wave
    float gv[NBG];
    {
      const int sb = lt >> 4, sl = lt & 15;
      float a = 0.f;
      const float* hb = &st[sb * STP + (sl << 2)];
      const float* wb = &wgv[sl << 2];
#pragma unroll
      for (int j = 0; j < 8; ++j) {
        const f32x4 hv = *(const f32x4*)&hb[j << 6];
        const f32x4 wv = *(const f32x4*)&wb[j << 6];
        a += hv.x * wv.x + hv.y * wv.y + hv.z * wv.z + hv.w * wv.w;
      }
      a += __shfl_xor(a, 1);
      a += __shfl_xor(a, 2);
      a += __shfl_xor(a, 4);
      a += __shfl_xor(a, 8);
#pragma unroll
      for (int b = 0; b < NBG; ++b) gv[b] = sigm(__shfl(a, b << 4) + bg_s);
    }
    // z = h-part + g * (A.Wx + S*Wx[256])
    f32x4 acc[NBG], pk[NBG];
#pragma unroll
    for (int b = 0; b < NBG; ++b) {
      acc[b].x = acc[b].y = acc[b].z = acc[b].w = 0.f;
      pk[b].x = pk[b].y = pk[b].z = pk[b].w = 0.f;
    }
#pragma unroll
    for (int i = 0; i < 16; ++i) {
      const f32x4 w = wh[i];
      const int d = (i << 5) + dc;
#pragma unroll
      for (int b = 0; b < NBG; ++b) acc[b] += st[b * STP + d] * w;
    }
#pragma unroll
    for (int i = 0; i < 8; ++i) {
      const f32x4 w = wxr[i];
      const int d = 512 + (i << 5) + dc;
#pragma unroll
      for (int b = 0; b < NBG; ++b) pk[b] += st[b * STP + d] * w;
    }
    if (dc == 0 && t > 0) {
#pragma unroll
      for (int b = 0; b < NBG; ++b) pk[b] += svl[(b << 9) + t - 1] * wxl;
    }
#pragma unroll
    for (int b = 0; b < NBG; ++b) {
      const float g = gv[b];
      acc[b].x += g * pk[b].x; acc[b].y += g * pk[b].y;
      acc[b].z += g * pk[b].z; acc[b].w += g * pk[b].w;
    }
#pragma unroll
    for (int m = 8; m <= 32; m <<= 1) {
#pragma unroll
      for (int b = 0; b < NBG; ++b) {
        acc[b].x += __shfl_xor(acc[b].x, m);
        acc[b].y += __shfl_xor(acc[b].y, m);
        acc[b].z += __shfl_xor(acc[b].z, m);
        acc[b].w += __shfl_xor(acc[b].w, m);
      }
    }
    if (lt < 8) {
      const int wv = tid >> 6;
#pragma unroll
      for (int b = 0; b < NBG; ++b)
        *(f32x4*)&zred[((wv * 8 + lt) * 4 + b) * 4] = acc[b];
    }
    __syncthreads();
    if (tid < 32) {   // LSTM pointwise: thread = (b,u)
      const int b = tid >> 3, u = tid & 7;
      float zg[4];
#pragma unroll
      for (int g = 0; g < 4; ++g) {
        const int cgi = g * 2 + (u >> 2), comp = u & 3;
        float z = bl_s[g * 8 + u];
#pragma unroll
        for (int wv = 0; wv < 4; ++wv) z += zred[((wv * 8 + cgi) * 4 + b) * 4 + comp];
        zg[g] = z;
      }
      const float gi = sigm(zg[0]);
      const float gf = sigm(zg[1]);
      const float go = sigm(zg[3]);
      const float cn = gf * c_s[tid] + gi * tanhf(zg[2]);
      const float hv = go * tanhf(cn);
      c_s[tid] = cn;
      if (t == TQ - 1) out[(size_t)(b0 + b) * HQ + wg * 8 + u] = hv;
      else st_dev(buf + (size_t)(pn * BQ + b0 + b) * BROW + wg * 8 + u, hv);
    }
    if (t == TQ - 1) break;
    // A-producer: key_w_{t-1} -> Mk_s[t-1]; A_t = sum_tau w_t[tau]*Mk[tau]
    if (t >= 1) {
#pragma unroll
      for (int k = 0; k < 8; ++k) wrow[yb * TQ + lt + (k << 6)] = wv8[k];
      float kw = 0.f;
      const float* hrow = &st[yb * STP];
      const float* wkr = &wkey_s[ykl * 520];
#pragma unroll
      for (int j = 0; j < 32; ++j) {
        const int u = ytc + (j << 4);
        kw += hrow[u] * wkr[u];
      }
      kw += __shfl_xor(kw, 1);
      kw += __shfl_xor(kw, 2);
      kw += __shfl_xor(kw, 4);
      kw += __shfl_xor(kw, 8);
      if (ytc == 0) Mk_s[(yb * 4 + ykl) * 520 + (t - 1)] = kw + bk_s[ykl];
      float accA = 0.f;
      const float* mk = &Mk_s[(yb * 4 + ykl) * 520];
      const float* wb = &wrow[yb * TQ];
#pragma unroll
      for (int j = 0; j < 32; ++j) {
        const int u = ytc + (j << 4);
        accA += wb[u] * mk[u];
      }
      accA += __shfl_xor(accA, 1);
      accA += __shfl_xor(accA, 2);
      accA += __shfl_xor(accA, 4);
      accA += __shfl_xor(accA, 8);
      if (ytc == 0)
        st_dev(buf + (size_t)(pn * BQ + b0 + yb) * BROW + 512 + wg * 4 + ykl, accA);
    }
    wg_signal_ctr(ctr);
  }
}

extern "C" void kernel_launch(void* const* d_in, const int* in_sizes, int n_in,
                              void* d_out, int out_size, void* d_ws, size_t ws_size,
                              hipStream_t stream) {
  (void)in_sizes; (void)n_in; (void)out_size; (void)ws_size;
  const float* X  = (const float*)d_in[0];
  const float* Wx = (const float*)d_in[1];
  const float* Wh = (const float*)d_in[2];
  const float* bl = (const float*)d_in[3];
  const float* Wk = (const float*)d_in[4];
  const float* bk = (const float*)d_in[5];
  const float* Wg = (const float*)d_in[6];
  const float* bg = (const float*)d_in[7];
  const float* cg = (const float*)d_in[8];
  const float* cb = (const float*)d_in[9];
  float* out = (float*)d_out;
  float* ws = (float*)d_ws;

  float* Gm = ws;                              // 32*512*512 = 8,388,608 f
  float* Sv = ws + (size_t)8388608;            // 32*512 = 16,384 f
  float* buf = ws + (size_t)8404992;           // 2*32*768 = 49,152 f
  int* ctrs = (int*)(ws + (size_t)8454144);    // 8 x 32 ints (128B/line)

  // zero Sv | state double-buffer | counters (one contiguous region)
  hipMemsetAsync(Sv, 0, (size_t)(16384 + 49152 + 256) * 4, stream);
  gram_k<<<dim3(36, BQ), dim3(256), 0, stream>>>(X, Gm);
  smax_k<<<dim3(TQ - 1, BQ), dim3(256), 0, stream>>>(Gm, Sv, cg, cb);

  void* args[] = {(void*)&Wx, (void*)&Wh, (void*)&bl, (void*)&Wk, (void*)&bk,
                  (void*)&Wg, (void*)&bg, (void*)&Gm, (void*)&Sv,
                  (void*)&buf, (void*)&ctrs, (void*)&out};
  hipError_t e = hipLaunchCooperativeKernel((const void*)esbn_scan, dim3(NWG),
                                            dim3(NTHR), args, 0, stream);
  if (e != hipSuccess) {
    esbn_scan<<<dim3(NWG), dim3(NTHR), 0, stream>>>(Wx, Wh, bl, Wk, bk, Wg, bg,
                                                    Gm, Sv, buf, ctrs, out);
  }
}

// Round 5
// 4188.076 us; speedup vs baseline: 1.2256x; 1.1093x over previous
//
#include <hip/hip_runtime.h>
#include <math.h>

#define BQ 32
#define TQ 512
#define DQ 768
#define KQ 256
#define HQ 512
#define G4 2048
#define BROW 768   // buf row: h[0:512) | A[512:768)
#define STP 772    // LDS state row stride (pad for banks)
#define NWG 512    // 8 groups x 64 WGs
#define NTHR 256
#define NBG 4      // batches per group

typedef float f32x4 __attribute__((ext_vector_type(4)));

// Device (agent) scope = sc1 on gfx950: coherent across XCDs.
__device__ __forceinline__ void waitcnt0() {
  asm volatile("s_waitcnt vmcnt(0) lgkmcnt(0)" ::: "memory");
}
__device__ __forceinline__ void st_dev(float* p, float v) {
  asm volatile("global_store_dword %0, %1, off sc1" :: "v"(p), "v"(v) : "memory");
}
__device__ __forceinline__ int ld_dev(const int* p) {
  int v;
  asm volatile("global_load_dword %0, %1, off sc1\ns_waitcnt vmcnt(0)"
               : "=v"(v) : "v"(p) : "memory");
  return v;
}
// one counter per group per phase, own 128B line; wave0 polls one address
__device__ __forceinline__ void wg_wait_ctr(const int* ctr, int target) {
  if (threadIdx.x < 64) {
    while (ld_dev(ctr) < target) __builtin_amdgcn_s_sleep(1);
  }
  __syncthreads();
}
__device__ __forceinline__ void wg_signal_ctr(int* ctr) {
  waitcnt0();
  __syncthreads();
  if (threadIdx.x == 0) atomicAdd(ctr, 1);
}
__device__ __forceinline__ float sigm(float x) { return 1.f / (1.f + __expf(-x)); }

// ---------------- P1: Gram matrix G[b][t][tau] = x_t . x_tau ----------------
__global__ void __launch_bounds__(256) gram_k(const float* __restrict__ X,
                                              float* __restrict__ Gm) {
  __shared__ __align__(16) float As[64 * 33];
  __shared__ __align__(16) float Bs[64 * 33];
  const int bid = blockIdx.x;
  const int b = blockIdx.y;
  int I = 0, base = 0;
  while (base + I + 1 <= bid) { base += I + 1; ++I; }
  const int J = bid - base;
  const int t0 = I * 64, u0 = J * 64;
  const float* Xb = X + (size_t)b * TQ * DQ;
  const int ty = threadIdx.x >> 4, tx = threadIdx.x & 15;
  const int sc = threadIdx.x & 31, sr = threadIdx.x >> 5;
  float acc[4][4];
#pragma unroll
  for (int i = 0; i < 4; ++i)
#pragma unroll
    for (int j = 0; j < 4; ++j) acc[i][j] = 0.f;
  for (int k0 = 0; k0 < DQ; k0 += 32) {
#pragma unroll
    for (int rr = 0; rr < 8; ++rr) {
      const int r = rr * 8 + sr;
      As[r * 33 + sc] = Xb[(size_t)(t0 + r) * DQ + k0 + sc];
      Bs[r * 33 + sc] = Xb[(size_t)(u0 + r) * DQ + k0 + sc];
    }
    __syncthreads();
#pragma unroll
    for (int k = 0; k < 32; ++k) {
      float av[4], bv[4];
#pragma unroll
      for (int i = 0; i < 4; ++i) av[i] = As[(ty * 4 + i) * 33 + k];
#pragma unroll
      for (int j = 0; j < 4; ++j) bv[j] = Bs[(tx * 4 + j) * 33 + k];
#pragma unroll
      for (int i = 0; i < 4; ++i)
#pragma unroll
        for (int j = 0; j < 4; ++j) acc[i][j] += av[i] * bv[j];
    }
    __syncthreads();
  }
  float* gb = Gm + (size_t)b * TQ * TQ;
#pragma unroll
  for (int i = 0; i < 4; ++i) {
    f32x4 o;
    o.x = acc[i][0]; o.y = acc[i][1]; o.z = acc[i][2]; o.w = acc[i][3];
    *(f32x4*)&gb[(size_t)(t0 + ty * 4 + i) * TQ + u0 + tx * 4] = o;
  }
}

// ---------------- P2: row softmax (tau < t) in place + S[b][t] ----------------
__global__ void __launch_bounds__(256) smax_k(float* __restrict__ Gm,
                                              float* __restrict__ Sv,
                                              const float* __restrict__ cgp,
                                              const float* __restrict__ cbp) {
  const int t = blockIdx.x + 1;   // 1..511
  const int b = blockIdx.y;
  const int tid = threadIdx.x;
  const int lane = tid & 63;
  const int wv = tid >> 6;
  __shared__ float row[TQ];
  __shared__ float r1[4], r2[4], r3[4];
  float* R = Gm + ((size_t)b * TQ + t) * TQ;
  const float cg = cgp[0], cb = cbp[0];
  for (int i = tid; i < t; i += 256) row[i] = R[i];
  __syncthreads();
  float m = -3e38f;
  for (int i = tid; i < t; i += 256) m = fmaxf(m, row[i]);
#pragma unroll
  for (int k = 1; k < 64; k <<= 1) m = fmaxf(m, __shfl_xor(m, k));
  if (lane == 0) r1[wv] = m;
  __syncthreads();
  m = fmaxf(fmaxf(r1[0], r1[1]), fmaxf(r1[2], r1[3]));
  float s = 0.f, sck = 0.f;
  for (int i = tid; i < t; i += 256) {
    const float r = row[i];
    const float e = __expf(r - m);
    const float ck = 1.f / (1.f + __expf(-(r * cg + cb)));
    row[i] = e; s += e; sck += e * ck;
  }
#pragma unroll
  for (int k = 1; k < 64; k <<= 1) { s += __shfl_xor(s, k); sck += __shfl_xor(sck, k); }
  if (lane == 0) { r2[wv] = s; r3[wv] = sck; }
  __syncthreads();
  s = r2[0] + r2[1] + r2[2] + r2[3];
  sck = r3[0] + r3[1] + r3[2] + r3[3];
  const float inv = 1.f / s;
  for (int i = tid; i < t; i += 256) R[i] = row[i] * inv;
  if (tid == 0) Sv[(size_t)b * TQ + t] = sck * inv;
}

// ---------------- K3: persistent recurrence, SPLIT h/A publishes -------------
// 8 groups (4 batches each) x 64 WGs x 256 thr. Producer: LSTM -> publish h ->
// ctrH; A-block -> publish A -> ctrA. Consumer: wait ctrH -> h-GEMM (A-block of
// producers hides under it) -> wait ctrA -> pk. A-block itself de-serialized:
// A-dot runs on old Mk (Mk[t-1] slot still zero) in parallel with kw-reduce;
// missing term added as wrow[t-1]*(kw+bk) afterwards.
__global__ void __launch_bounds__(NTHR, 2) esbn_scan(
    const float* __restrict__ Wx, const float* __restrict__ Wh,
    const float* __restrict__ bl, const float* __restrict__ Wk,
    const float* __restrict__ bk, const float* __restrict__ Wg,
    const float* __restrict__ bgp, const float* __restrict__ Wmat,
    const float* __restrict__ Sv, float* buf, int* ctrs,
    float* __restrict__ out) {
  __shared__ __align__(16) float st[NBG * STP];      // [h | A] per local batch
  __shared__ __align__(16) float wrow[NBG * TQ];     // softmax row t
  __shared__ __align__(16) float Mk_s[16 * 520];     // [b][kl][tau] WG-local key mem
  __shared__ __align__(16) float wkey_s[4 * 520];
  __shared__ __align__(16) float wgv[HQ];
  __shared__ __align__(16) float svl[NBG * TQ];      // Sv rows for this group
  __shared__ __align__(16) float zred[4 * 8 * 4 * 4];
  __shared__ float c_s[NBG * 8];
  __shared__ float bl_s[32];
  __shared__ float bk_s[4];
  __shared__ float bg_s;

  const int tid = threadIdx.x;
  const int wg = blockIdx.x & 63;
  const int grp = blockIdx.x >> 6;   // 0..7
  const int b0 = grp * NBG;
  const int dc = tid >> 3;   // d-chunk 0..31
  const int cg = tid & 7;    // col group (4 cols)

  int colg[4];
#pragma unroll
  for (int j = 0; j < 4; ++j) {
    const int c = cg * 4 + j;
    colg[j] = (c >> 3) * HQ + wg * 8 + (c & 7);
  }
  f32x4 wh[16], wxr[8], wxl;
#pragma unroll
  for (int i = 0; i < 16; ++i) {
    const int d = (i << 5) + dc;
    wh[i].x = Wh[(size_t)d * G4 + colg[0]];
    wh[i].y = Wh[(size_t)d * G4 + colg[1]];
    wh[i].z = Wh[(size_t)d * G4 + colg[2]];
    wh[i].w = Wh[(size_t)d * G4 + colg[3]];
  }
#pragma unroll
  for (int i = 0; i < 8; ++i) {
    const int d = (i << 5) + dc;
    wxr[i].x = Wx[(size_t)d * G4 + colg[0]];
    wxr[i].y = Wx[(size_t)d * G4 + colg[1]];
    wxr[i].z = Wx[(size_t)d * G4 + colg[2]];
    wxr[i].w = Wx[(size_t)d * G4 + colg[3]];
  }
  wxl.x = wxl.y = wxl.z = wxl.w = 0.f;
  if (dc == 0) {
    wxl.x = Wx[(size_t)256 * G4 + colg[0]];
    wxl.y = Wx[(size_t)256 * G4 + colg[1]];
    wxl.z = Wx[(size_t)256 * G4 + colg[2]];
    wxl.w = Wx[(size_t)256 * G4 + colg[3]];
  }
  for (int i = tid; i < NBG * STP; i += NTHR) st[i] = 0.f;
  for (int i = tid; i < 16 * 520; i += NTHR) Mk_s[i] = 0.f;
  for (int i = tid; i < 4 * 520; i += NTHR) {
    const int kl = i / 520, u = i - kl * 520;
    wkey_s[i] = (u < HQ) ? Wk[(size_t)u * KQ + wg * 4 + kl] : 0.f;
  }
  for (int i = tid; i < HQ; i += NTHR) wgv[i] = Wg[i];
  for (int i = tid; i < NBG * TQ; i += NTHR)
    svl[i] = Sv[(size_t)(b0 + (i >> 9)) * TQ + (i & 511)];
  if (tid < 32) bl_s[tid] = bl[(tid >> 3) * HQ + wg * 8 + (tid & 7)];
  if (tid < 4) bk_s[tid] = bk[wg * 4 + tid];
  if (tid == 0) bg_s = bgp[0];
  if (tid < NBG * 8) c_s[tid] = 0.f;
  __syncthreads();

  int* ctrH = ctrs + grp * 64;       // own 128B line
  int* ctrA = ctrs + grp * 64 + 32;  // own 128B line
  const int yb = tid >> 6;          // batch 0..3 (wave)
  const int ykl = (tid >> 4) & 3;   // key lane 0..3
  const int ytc = tid & 15;         // tau/u chunk 0..15
  const int lt = tid & 63;

  for (int t = 0; t < TQ; ++t) {
    const int p = t & 1, pn = p ^ 1;
    // prefetch softmax row t into regs (flag-independent; consumed in A-block)
    float wv8[8];
    const bool rowv = (t >= 1) && (t < TQ - 1);
    if (rowv) {
      const float* wr = Wmat + ((size_t)(b0 + yb) * TQ + t) * TQ + lt;
#pragma unroll
      for (int k = 0; k < 8; ++k) wv8[k] = wr[k << 6];
    }
    if (t > 0) {
      wg_wait_ctr(ctrH, 64 * t);   // h_{t-1} published by all 64 WGs
      const float* base = buf + (size_t)(p * BQ + b0) * BROW;
      f32x4 v0, v1;
      const int i0 = tid, i1 = tid + 256;               // h: 512 f4 chunks
      const float* q0 = base + ((i0 >> 7) * BROW) + ((i0 & 127) << 2);
      const float* q1 = base + ((i1 >> 7) * BROW) + ((i1 & 127) << 2);
      asm volatile("global_load_dwordx4 %0, %1, off sc1" : "=v"(v0) : "v"(q0));
      asm volatile("global_load_dwordx4 %0, %1, off sc1" : "=v"(v1) : "v"(q1));
      asm volatile("s_waitcnt vmcnt(0)" : "+v"(v0), "+v"(v1) : : "memory");
      *(f32x4*)&st[((i0 >> 7) * STP) + ((i0 & 127) << 2)] = v0;
      *(f32x4*)&st[((i1 >> 7) * STP) + ((i1 & 127) << 2)] = v1;
    }
    __syncthreads();   // st h ready
    // h-part of z (producers' A-block hides under this GEMM)
    f32x4 acc[NBG];
#pragma unroll
    for (int b = 0; b < NBG; ++b) { acc[b].x = acc[b].y = acc[b].z = acc[b].w = 0.f; }
#pragma unroll
    for (int i = 0; i < 16; ++i) {
      const f32x4 w = wh[i];
      const int d = (i << 5) + dc;
#pragma unroll
      for (int b = 0; b < NBG; ++b) acc[b] += st[b * STP + d] * w;
    }
    // g_{t-1}[0..3] per-wave: 16-lane sub-group per batch, broadcast in-wave
    float gv[NBG];
    {
      const int sb = lt >> 4, sl = lt & 15;
      float a = 0.f;
      const float* hb = &st[sb * STP];
      const float* wb = wgv;
#pragma unroll
      for (int j = 0; j < 8; ++j) {
        const int u = sl + (j << 4) + ((j & 3) << 7);  // spread, 2-way banks
        a += hb[u] * wb[u];
      }
      // NOTE: the index set above must cover 0..511 exactly once per sub-group.
      a = 0.f;
#pragma unroll
      for (int j = 0; j < 32; ++j) {
        const int u = sl + (j << 4);
        a += hb[u] * wb[u];
      }
      a += __shfl_xor(a, 1);
      a += __shfl_xor(a, 2);
      a += __shfl_xor(a, 4);
      a += __shfl_xor(a, 8);
#pragma unroll
      for (int b = 0; b < NBG; ++b) gv[b] = sigm(__shfl(a, b << 4) + bg_s);
    }
    if (t > 0) {
      wg_wait_ctr(ctrA, 64 * t);   // A_{t-1} published (usually already true)
      const float* base = buf + (size_t)(p * BQ + b0) * BROW;
      f32x4 v2;
      const float* q2 = base + ((tid >> 6) * BROW) + 512 + ((tid & 63) << 2);
      asm volatile("global_load_dwordx4 %0, %1, off sc1" : "=v"(v2) : "v"(q2));
      asm volatile("s_waitcnt vmcnt(0)" : "+v"(v2) : : "memory");
      *(f32x4*)&st[((tid >> 6) * STP) + 512 + ((tid & 63) << 2)] = v2;
    }
    __syncthreads();   // st A ready
    // key_r part: pk = A.Wx + S*Wx[256]; z += g*pk
    f32x4 pk[NBG];
#pragma unroll
    for (int b = 0; b < NBG; ++b) { pk[b].x = pk[b].y = pk[b].z = pk[b].w = 0.f; }
#pragma unroll
    for (int i = 0; i < 8; ++i) {
      const f32x4 w = wxr[i];
      const int d = 512 + (i << 5) + dc;
#pragma unroll
      for (int b = 0; b < NBG; ++b) pk[b] += st[b * STP + d] * w;
    }
    if (dc == 0 && t > 0) {
#pragma unroll
      for (int b = 0; b < NBG; ++b) pk[b] += svl[(b << 9) + t - 1] * wxl;
    }
#pragma unroll
    for (int b = 0; b < NBG; ++b) {
      const float g = gv[b];
      acc[b].x += g * pk[b].x; acc[b].y += g * pk[b].y;
      acc[b].z += g * pk[b].z; acc[b].w += g * pk[b].w;
    }
#pragma unroll
    for (int m = 8; m <= 32; m <<= 1) {
#pragma unroll
      for (int b = 0; b < NBG; ++b) {
        acc[b].x += __shfl_xor(acc[b].x, m);
        acc[b].y += __shfl_xor(acc[b].y, m);
        acc[b].z += __shfl_xor(acc[b].z, m);
        acc[b].w += __shfl_xor(acc[b].w, m);
      }
    }
    if (lt < 8) {
      const int wv = tid >> 6;
#pragma unroll
      for (int b = 0; b < NBG; ++b)
        *(f32x4*)&zred[((wv * 8 + lt) * 4 + b) * 4] = acc[b];
    }
    __syncthreads();
    if (tid < 32) {   // LSTM pointwise: thread = (b,u)
      const int b = tid >> 3, u = tid & 7;
      float zg[4];
#pragma unroll
      for (int g = 0; g < 4; ++g) {
        const int cgi = g * 2 + (u >> 2), comp = u & 3;
        float z = bl_s[g * 8 + u];
#pragma unroll
        for (int wv = 0; wv < 4; ++wv) z += zred[((wv * 8 + cgi) * 4 + b) * 4 + comp];
        zg[g] = z;
      }
      const float gi = sigm(zg[0]);
      const float gf = sigm(zg[1]);
      const float go = sigm(zg[3]);
      const float cn = gf * c_s[tid] + gi * tanhf(zg[2]);
      const float hv = go * tanhf(cn);
      c_s[tid] = cn;
      if (t == TQ - 1) out[(size_t)(b0 + b) * HQ + wg * 8 + u] = hv;
      else st_dev(buf + (size_t)(pn * BQ + b0 + b) * BROW + wg * 8 + u, hv);
    }
    if (t == TQ - 1) break;
    wg_signal_ctr(ctrH);   // h_t visible -> consumers start their h-GEMM
    // A-block (off the h critical path): A_t on old Mk, kw folded in at the end
    if (t >= 1) {
#pragma unroll
      for (int k = 0; k < 8; ++k) wrow[yb * TQ + lt + (k << 6)] = wv8[k];
      float kw = 0.f, accA = 0.f;
      const float* hrow = &st[yb * STP];
      const float* wkr = &wkey_s[ykl * 520];
      const float* mk = &Mk_s[(yb * 4 + ykl) * 520];
      const float* wb = &wrow[yb * TQ];
#pragma unroll
      for (int j = 0; j < 32; ++j) {
        const int u = ytc + (j << 4);
        kw += hrow[u] * wkr[u];
        accA += wb[u] * mk[u];    // Mk[t-1] slot still zero: term added below
      }
#pragma unroll
      for (int m = 1; m <= 8; m <<= 1) {
        kw += __shfl_xor(kw, m);
        accA += __shfl_xor(accA, m);
      }
      kw += bk_s[ykl];
      accA += wb[t - 1] * kw;     // the tau = t-1 contribution
      if (ytc == 0) {
        st_dev(buf + (size_t)(pn * BQ + b0 + yb) * BROW + 512 + wg * 4 + ykl, accA);
        Mk_s[(yb * 4 + ykl) * 520 + (t - 1)] = kw;
      }
    }
    wg_signal_ctr(ctrA);
  }
}

extern "C" void kernel_launch(void* const* d_in, const int* in_sizes, int n_in,
                              void* d_out, int out_size, void* d_ws, size_t ws_size,
                              hipStream_t stream) {
  (void)in_sizes; (void)n_in; (void)out_size; (void)ws_size;
  const float* X  = (const float*)d_in[0];
  const float* Wx = (const float*)d_in[1];
  const float* Wh = (const float*)d_in[2];
  const float* bl = (const float*)d_in[3];
  const float* Wk = (const float*)d_in[4];
  const float* bk = (const float*)d_in[5];
  const float* Wg = (const float*)d_in[6];
  const float* bg = (const float*)d_in[7];
  const float* cg = (const float*)d_in[8];
  const float* cb = (const float*)d_in[9];
  float* out = (float*)d_out;
  float* ws = (float*)d_ws;

  float* Gm = ws;                              // 32*512*512 = 8,388,608 f
  float* Sv = ws + (size_t)8388608;            // 32*512 = 16,384 f
  float* buf = ws + (size_t)8404992;           // 2*32*768 = 49,152 f
  int* ctrs = (int*)(ws + (size_t)8454144);    // 8 x 64 ints (2 x 128B/group)

  // zero Sv | state double-buffer | counters (one contiguous region)
  hipMemsetAsync(Sv, 0, (size_t)(16384 + 49152 + 512) * 4, stream);
  gram_k<<<dim3(36, BQ), dim3(256), 0, stream>>>(X, Gm);
  smax_k<<<dim3(TQ - 1, BQ), dim3(256), 0, stream>>>(Gm, Sv, cg, cb);

  void* args[] = {(void*)&Wx, (void*)&Wh, (void*)&bl, (void*)&Wk, (void*)&bk,
                  (void*)&Wg, (void*)&bg, (void*)&Gm, (void*)&Sv,
                  (void*)&buf, (void*)&ctrs, (void*)&out};
  hipError_t e = hipLaunchCooperativeKernel((const void*)esbn_scan, dim3(NWG),
                                            dim3(NTHR), args, 0, stream);
  if (e != hipSuccess) {
    esbn_scan<<<dim3(NWG), dim3(NTHR), 0, stream>>>(Wx, Wh, bl, Wk, bk, Wg, bg,
                                                    Gm, Sv, buf, ctrs, out);
  }
}